// Round 1
// baseline (748.060 us; speedup 1.0000x reference)
//
#include <hip/hip_runtime.h>
#include <math.h>

#define NUMPIX 256
#define NUMBIN 367
#define NUMTHETA 360
#define NS 4
#define NT 367
#define NPIX2 (NUMPIX * NUMPIX)          // 65536
#define NRAYS_ALL (NUMTHETA * NUMBIN)    // 132120
#define NANG_SUB (NUMTHETA / NS)         // 90
#define NRAYS_SUB (NANG_SUB * NUMBIN)    // 33030

#define CDET 183.0f
#define CPIX 127.5f
#define TOFF 183.0f                      // (NT-1)/2
#define DEN_EPS 1e-6f
#define EPS_F 2.2204460492503131e-16f    // float64 eps
#define RES2_THRESH 1e-4f                // (0.01)^2

// ---- workspace layout (in floats) ----
#define OFF_COS  0
#define OFF_SIN  (OFF_COS + NUMTHETA)            // 360
#define OFF_MINV (OFF_SIN + NUMTHETA)            // 720
#define OFF_DINV (OFF_MINV + NRAYS_ALL)          // 720+132120
#define OFF_FK   (OFF_DINV + NS * NPIX2)
#define OFF_DIFF (OFF_FK + NPIX2)
#define OFF_RES  (OFF_DIFF + NRAYS_SUB)

// ---------------- trig setup ----------------
__global__ void setup_trig(float* __restrict__ cosA, float* __restrict__ sinA) {
    int a = blockIdx.x * blockDim.x + threadIdx.x;
    if (a < NUMTHETA) {
        // numpy: theta32 = float32(deg2rad(a)); cos/sin in float32
        float th = (float)((double)a * 0.017453292519943295);
        cosA[a] = (float)cos((double)th);
        sinA[a] = (float)sin((double)th);
    }
}

// ---------------- forward projection ----------------
// bilinear sample of img at (col=x, row=y), constant-0 outside
__device__ __forceinline__ float bilerp_img(const float* __restrict__ img,
                                            float x, float y) {
    float fx = floorf(x), fy = floorf(y);
    float wx = x - fx, wy = y - fy;
    int c0 = (int)fx, r0 = (int)fy;
    int c1 = c0 + 1, r1 = r0 + 1;
    bool c0v = ((unsigned)c0 < NUMPIX), c1v = ((unsigned)c1 < NUMPIX);
    bool r0v = ((unsigned)r0 < NUMPIX), r1v = ((unsigned)r1 < NUMPIX);
    float v00 = (r0v && c0v) ? img[r0 * NUMPIX + c0] : 0.0f;
    float v01 = (r0v && c1v) ? img[r0 * NUMPIX + c1] : 0.0f;
    float v10 = (r1v && c0v) ? img[r1 * NUMPIX + c0] : 0.0f;
    float v11 = (r1v && c1v) ? img[r1 * NUMPIX + c1] : 0.0f;
    return (v00 * (1.0f - wx) + v01 * wx) * (1.0f - wy) +
           (v10 * (1.0f - wx) + v11 * wx) * wy;
}

__device__ __forceinline__ float bilerp_ones(float x, float y) {
    float fx = floorf(x), fy = floorf(y);
    float wx = x - fx, wy = y - fy;
    int c0 = (int)fx, r0 = (int)fy;
    int c1 = c0 + 1, r1 = r0 + 1;
    bool c0v = ((unsigned)c0 < NUMPIX), c1v = ((unsigned)c1 < NUMPIX);
    bool r0v = ((unsigned)r0 < NUMPIX), r1v = ((unsigned)r1 < NUMPIX);
    float v = 0.0f;
    if (r0v && c0v) v += (1.0f - wx) * (1.0f - wy);
    if (r0v && c1v) v += wx * (1.0f - wy);
    if (r1v && c0v) v += (1.0f - wx) * wy;
    if (r1v && c1v) v += wx * wy;
    return v;
}

// MODE 0: Minv = max(FP(ones), 1e-6) -> out[angle*NUMBIN+bin]
// MODE 1: diffs = (sino - FP(img)) / Minv -> out[ai*NUMBIN+bin]
// MODE 2: residual: atomicAdd(out, sum((FP(img) - sino)^2))
template <int MODE>
__global__ void fp_kernel(const float* __restrict__ img,
                          const float* __restrict__ sino,
                          const float* __restrict__ minv,
                          float* __restrict__ out,
                          const float* __restrict__ cosA,
                          const float* __restrict__ sinA,
                          int angleStart, int angleStride, int nRays) {
    const int wid = threadIdx.x >> 6;
    const int lane = threadIdx.x & 63;
    __shared__ float part[4];
    float wacc = 0.0f;  // MODE 2 per-wave accumulator (lane 0)

    for (int ray = blockIdx.x * 4 + wid; ray < nRays; ray += gridDim.x * 4) {
        int ai = ray / NUMBIN;
        int bin = ray - ai * NUMBIN;
        int angle = angleStart + ai * angleStride;
        float ca = cosA[angle], sa = sinA[angle];
        float s = (float)bin - CDET;
        float acc = 0.0f;
        for (int t = lane; t < NT; t += 64) {
            float tt = (float)t - TOFF;
            float x = s * ca - tt * sa + CPIX;
            float y = s * sa + tt * ca + CPIX;
            acc += (MODE == 0) ? bilerp_ones(x, y) : bilerp_img(img, x, y);
        }
        #pragma unroll
        for (int off = 32; off; off >>= 1) acc += __shfl_down(acc, off);
        if (lane == 0) {
            if (MODE == 0) {
                out[angle * NUMBIN + bin] = fmaxf(acc, DEN_EPS);
            } else if (MODE == 1) {
                out[ai * NUMBIN + bin] =
                    (sino[angle * NUMBIN + bin] - acc) / minv[angle * NUMBIN + bin];
            } else {
                float d = acc - sino[angle * NUMBIN + bin];
                wacc += d * d;
            }
        }
    }
    if (MODE == 2) {
        if (lane == 0) part[wid] = wacc;
        __syncthreads();
        if (threadIdx.x == 0) {
            float s2 = part[0] + part[1] + part[2] + part[3];
            atomicAdd(out, s2);
        }
    }
}

// ---------------- backprojection ----------------
// Dinv[j] = max(BP_j(ones), 1e-6)
__global__ void dinv_kernel(float* __restrict__ dinv,
                            const float* __restrict__ cosA,
                            const float* __restrict__ sinA) {
    int p = blockIdx.x * blockDim.x + threadIdx.x;
    int j = blockIdx.y;
    int px = p & (NUMPIX - 1), py = p >> 8;
    float X = (float)px - CPIX, Y = (float)py - CPIX;
    float acc = 0.0f;
    for (int i = 0; i < NANG_SUB; i++) {
        int angle = j + NS * i;
        float ca = cosA[angle], sa = sinA[angle];
        float sd = X * ca + Y * sa + CDET;
        float f0 = floorf(sd);
        float w = sd - f0;
        int i0 = (int)f0;
        float v0 = ((unsigned)i0 < NUMBIN) ? 1.0f : 0.0f;
        float v1 = ((unsigned)(i0 + 1) < NUMBIN) ? 1.0f : 0.0f;
        acc += v0 * (1.0f - w) + v1 * w;
    }
    dinv[j * NPIX2 + p] = fmaxf(acc, DEN_EPS);
}

// fk += clamp1000(BP_j(diffs)) / Dinv[j]; optional fk = max(fk, EPS)
__global__ void bp_update_kernel(float* __restrict__ fk,
                                 const float* __restrict__ g,      // diffs [90,367]
                                 const float* __restrict__ dinv_j, // [65536]
                                 const float* __restrict__ cosA,
                                 const float* __restrict__ sinA,
                                 int j, int doClamp) {
    int p = blockIdx.x * blockDim.x + threadIdx.x;
    int px = p & (NUMPIX - 1), py = p >> 8;
    float X = (float)px - CPIX, Y = (float)py - CPIX;
    float acc = 0.0f;
    for (int i = 0; i < NANG_SUB; i++) {
        int angle = j + NS * i;
        float ca = cosA[angle], sa = sinA[angle];
        float sd = X * ca + Y * sa + CDET;
        float f0 = floorf(sd);
        float w = sd - f0;
        int i0 = (int)f0;
        float v0 = ((unsigned)i0 < NUMBIN) ? g[i * NUMBIN + i0] : 0.0f;
        float v1 = ((unsigned)(i0 + 1) < NUMBIN) ? g[i * NUMBIN + i0 + 1] : 0.0f;
        acc += v0 * (1.0f - w) + v1 * w;
    }
    float bp = (fabsf(acc) > 1000.0f) ? 0.0f : acc;
    float v = fk[p] + bp / dinv_j[p];
    if (doClamp) v = fmaxf(v, EPS_F);
    fk[p] = v;
}

// ---------------- misc ----------------
__global__ void init_kernel(float* __restrict__ fk, float* __restrict__ fcur,
                            const float* __restrict__ f0) {
    int p = blockIdx.x * blockDim.x + threadIdx.x;
    float v = f0[p];
    fk[p] = v;
    fcur[p] = v;
}

__global__ void zero_kernel(float* __restrict__ r) { *r = 0.0f; }

__global__ void select_kernel(float* __restrict__ fcur, float* __restrict__ fk,
                              const float* __restrict__ res2) {
    int p = blockIdx.x * blockDim.x + threadIdx.x;
    bool upd = (*res2 > RES2_THRESH);  // res = sqrt(res2) > 0.01
    if (upd) fcur[p] = fk[p];
    else     fk[p] = fcur[p];
}

extern "C" void kernel_launch(void* const* d_in, const int* in_sizes, int n_in,
                              void* d_out, int out_size, void* d_ws, size_t ws_size,
                              hipStream_t stream) {
    const float* f0 = (const float*)d_in[0];     // [256,256]
    const float* sino = (const float*)d_in[1];   // [360,367]
    float* fcur = (float*)d_out;                 // [256,256] output "f"
    float* ws = (float*)d_ws;

    float* cosA = ws + OFF_COS;
    float* sinA = ws + OFF_SIN;
    float* minv = ws + OFF_MINV;   // [360,367] indexed by global angle
    float* dinv = ws + OFF_DINV;   // [4,256,256]
    float* fk   = ws + OFF_FK;     // [256,256]
    float* diff = ws + OFF_DIFF;   // [90,367]
    float* res2 = ws + OFF_RES;    // scalar

    setup_trig<<<6, 64, 0, stream>>>(cosA, sinA);

    // Minv over all 360 angles (one dispatch)
    fp_kernel<0><<<(NRAYS_ALL + 3) / 4, 256, 0, stream>>>(
        nullptr, nullptr, nullptr, minv, cosA, sinA, 0, 1, NRAYS_ALL);

    // Dinv for 4 subsets
    dinv_kernel<<<dim3(NPIX2 / 256, NS), 256, 0, stream>>>(dinv, cosA, sinA);

    init_kernel<<<NPIX2 / 256, 256, 0, stream>>>(fk, fcur, f0);

    for (int iter = 0; iter < 2; iter++) {
        for (int j = 0; j < NS; j++) {
            fp_kernel<1><<<(NRAYS_SUB + 3) / 4, 256, 0, stream>>>(
                fk, sino, minv, diff, cosA, sinA, j, NS, NRAYS_SUB);
            bp_update_kernel<<<NPIX2 / 256, 256, 0, stream>>>(
                fk, diff, dinv + j * NPIX2, cosA, sinA, j, (j == NS - 1) ? 1 : 0);
        }
        zero_kernel<<<1, 1, 0, stream>>>(res2);
        fp_kernel<2><<<1024, 256, 0, stream>>>(
            fk, sino, nullptr, res2, cosA, sinA, 0, 1, NRAYS_ALL);
        select_kernel<<<NPIX2 / 256, 256, 0, stream>>>(fcur, fk, res2);
    }
}